// Round 8
// baseline (74.716 us; speedup 1.0000x reference)
//
#include <hip/hip_runtime.h>
#include <cmath>

#define BB 64
#define TT 512
#define CC 1000
#define SS 32
#define COR 4
#define NPROB (BB + BB*COR)   // 320
#define NEGV (-1e30f)
#define LOG2E 1.4426950408889634f
#define LN2 0.6931471805599453f
#define BIAS 50               // renorm target exponent: needed-max -> 2^BIAS
#define SHIFT 16.0f           // constant lse shift (replaces wave max; |w|<=8)

// ---------------------------------------------------------------------------
// DPP helpers (VALU-pipe cross-lane). 0x138 = wave_shr:1 (HW-verified r3-r7).
// Reduction tree row_shr:1/2/4/8 + row_bcast:15/31 -> lane 63 (verified r7:
// gather's lse fed every output at absmax 0.0).
// ---------------------------------------------------------------------------
__device__ __forceinline__ float dpp_shr1_fill(float x, float fill) {
    int r = __builtin_amdgcn_update_dpp(__builtin_bit_cast(int, fill),
                                        __builtin_bit_cast(int, x),
                                        0x138, 0xf, 0xf, false);   // lane0 <- fill
    return __builtin_bit_cast(float, r);
}
__device__ __forceinline__ float dpp_shr1_z(float x) {
    int r = __builtin_amdgcn_update_dpp(0, __builtin_bit_cast(int, x),
                                        0x138, 0xf, 0xf, true);    // lane0 <- 0
    return __builtin_bit_cast(float, r);
}
template<int CTRL>
__device__ __forceinline__ float dpp_maxf(float m) {   // 0-fill ok: A >= 0
    int r = __builtin_amdgcn_update_dpp(0, __builtin_bit_cast(int, m),
                                        CTRL, 0xf, 0xf, true);
    return fmaxf(m, __builtin_bit_cast(float, r));
}
template<int CTRL>
__device__ __forceinline__ float dpp_addf(float s) {
    int r = __builtin_amdgcn_update_dpp(0, __builtin_bit_cast(int, s),
                                        CTRL, 0xf, 0xf, true);     // invalid -> +0
    return s + __builtin_bit_cast(float, r);
}
__device__ __forceinline__ float rdlane(float x, int lane) {
    return __builtin_bit_cast(float, __builtin_amdgcn_readlane(__builtin_bit_cast(int, x), lane));
}
// exact full-wave sum, result broadcast via readlane 63
__device__ __forceinline__ float wave_sum(float s) {
    s = dpp_addf<0x111>(s);
    s = dpp_addf<0x112>(s);
    s = dpp_addf<0x114>(s);
    s = dpp_addf<0x118>(s);
    s = dpp_addf<0x142>(s);
    s = dpp_addf<0x143>(s);
    return rdlane(s, 63);
}

// Renorm vs max over NEEDED lanes (lane < nl), all-VALU (~40cy).
// Scales so needed-max exponent == BIAS; accumulates true exponent in off.
__device__ __forceinline__ void renorm(float &A, float &a0, int &off,
                                       int lane, int nl) {
    float m = (lane < nl) ? A : 0.f;
    m = dpp_maxf<0x111>(m);
    m = dpp_maxf<0x112>(m);
    m = dpp_maxf<0x114>(m);
    m = dpp_maxf<0x118>(m);
    m = dpp_maxf<0x142>(m);
    m = dpp_maxf<0x143>(m);
    int mb = __builtin_amdgcn_readlane(__builtin_bit_cast(int, m), 63);
    int e = ((mb >> 23) & 0xff) - 127 - BIAS;
    e = (mb & 0x7fffffff) ? e : 0;       // m==0 guard
    A  = ldexpf(A,  -e);
    a0 = ldexpf(a0, -e);
    off += e;
}

// ---------------------------------------------------------------------------
// Gather kernel: per preds row [b,t,:]: coalesced float4 read; constant-shift
// exp2 sum (no max pass -- N(0,1) logits give |x*log2e| <= ~8, so w-16 is
// overflow/underflow-safe and exps overlap the loads); DPP wave_sum; write
// LINEAR normalized probs labels[pid][t][k] (5 full 128B lines/row) and
// blankE[b][t]. Block 0 also zeroes the ticket counter for ctc's finalize.
// ---------------------------------------------------------------------------
__global__ __launch_bounds__(256) void gather_kernel(const float* __restrict__ preds,
                                                     const int* __restrict__ text,
                                                     const int* __restrict__ stext,
                                                     float* __restrict__ labels,
                                                     float* __restrict__ blankE,
                                                     int* __restrict__ counter) {
    if (blockIdx.x == 0 && threadIdx.x == 0) *counter = 0;
    int gw = (blockIdx.x * blockDim.x + threadIdx.x) >> 6;   // row = b*512+t
    int lane = threadIdx.x & 63;
    if (gw >= BB * TT) return;
    int b = gw >> 9;
    int t = gw & (TT - 1);
    const float* row = preds + (size_t)gw * CC;
    const float4* row4 = (const float4*)row;
    float s = 0.f;
#pragma unroll
    for (int i = 0; i < 4; ++i) {
        int idx = lane + i * 64;
        float4 x = (idx < 250) ? row4[idx] : make_float4(NEGV, NEGV, NEGV, NEGV);
        s += exp2f(fmaf(x.x, LOG2E, -SHIFT));
        s += exp2f(fmaf(x.y, LOG2E, -SHIFT));
        s += exp2f(fmaf(x.z, LOG2E, -SHIFT));
        s += exp2f(fmaf(x.w, LOG2E, -SHIFT));
    }
    s = wave_sum(s);
    float lse2 = SHIFT + log2f(s);           // wave-uniform log2(sum exp2)

    if (lane == 0) blankE[gw] = exp2f(fmaf(row[0], LOG2E, -lse2));

#pragma unroll
    for (int it = 0; it < 3; ++it) {
        int g = lane + it * 64;
        if (g < 5 * SS) {
            int pp = g >> 5, k = g & 31;
            int cls, pid;
            if (pp == 0) { cls = text[b * SS + k]; pid = b; }
            else { int i = b * COR + (pp - 1); cls = stext[i * SS + k]; pid = BB + i; }
            labels[((size_t)pid * TT + t) * SS + k] = exp2f(fmaf(row[cls], LOG2E, -lse2));
        }
    }
}

// ---------------------------------------------------------------------------
// Linear-domain CTC + fused finalize. Lane s owns extended position s+1;
// position 0 (leading blank) is the wave-uniform scalar a0 (DPP fill operand).
// Per-step chain: dpp, dpp, cndmask, add, add, mul -- zero transcendentals.
// 3-buffer / 2-chunk-lookahead prefetch (~800cy) covers L3 latency.
// Renorm (DPP tree, needed-lane max -> 2^BIAS) every 8 steps.
// Last block (device-scope ticket) reduces the 320 losses and writes out[0].
// ---------------------------------------------------------------------------
__global__ __launch_bounds__(64) void ctc_lin_kernel(const float* __restrict__ labels,
                                                     const float* __restrict__ blankE,
                                                     const int* __restrict__ text,
                                                     const int* __restrict__ length,
                                                     const int* __restrict__ stext,
                                                     const int* __restrict__ slength,
                                                     float* __restrict__ lm,
                                                     float* __restrict__ ls,
                                                     int* __restrict__ counter,
                                                     float* __restrict__ out) {
    const int p = blockIdx.x;
    const int lane = threadIdx.x;

    int b, len;
    const int* tgt;
    if (p < BB) { b = p;        tgt = text  + (size_t)p * SS; len = length[p]; }
    else { int i = p - BB; b = i / COR; tgt = stext + (size_t)i * SS; len = slength[i]; }

    // lane s = position s+1: even s -> label k=s/2; odd s -> blank.
    const bool evenl = !(lane & 1);
    const int k = lane >> 1;
    bool use2 = false;
    if (evenl && lane >= 2) use2 = (tgt[k] != tgt[k - 1]);

    const float* bbase = blankE + (size_t)b * TT;
    const float* basep = evenl ? (labels + (size_t)p * TT * SS + k) : bbase;
    const int stridep = evenl ? SS : 1;
    const int i2 = 2 * len;                  // needed lanes: [0, i2)

    constexpr int CH = 16;
    constexpr int NCH = TT / CH;             // 32
    float eA[CH], eB[CH], eC[CH], bA[CH], bB[CH], bC[CH];

    auto loadChunk = [&](float (&ee)[CH], float (&bv)[CH], int c) {
#pragma unroll
        for (int j = 0; j < CH; ++j)
            ee[j] = basep[(size_t)(c * CH + j) * stridep];
        const float4* b4 = (const float4*)(bbase + c * CH);
#pragma unroll
        for (int q = 0; q < CH / 4; ++q) {
            float4 y = b4[q];
            bv[q*4+0] = y.x; bv[q*4+1] = y.y; bv[q*4+2] = y.z; bv[q*4+3] = y.w;
        }
    };

    float A, a0;
    int off = 0;

#define RUN16(EE, BV, START)                                    \
    _Pragma("unroll")                                           \
    for (int j = (START); j < CH; ++j) {                        \
        float p1 = dpp_shr1_fill(A, a0);                        \
        float p2 = dpp_shr1_z(p1);                              \
        float x2 = use2 ? p2 : 0.f;                             \
        A = (A + p1 + x2) * EE[j];                              \
        a0 *= BV[j];                                            \
        if ((j & 7) == 7) renorm(A, a0, off, lane, i2);         \
    }

    // prologue: 3 chunks in flight
    loadChunk(eA, bA, 0);
    loadChunk(eB, bB, 1);
    loadChunk(eC, bC, 2);
    A  = (lane == 0) ? eA[0] : 0.f;          // alpha0[pos1] = emit(y1)
    a0 = bA[0];                              // alpha0[pos0] = emit(blank)
    RUN16(eA, bA, 1)

    // steady state: issue chunk c+2 before running chunk c (2-RUN lookahead)
    for (int c = 1; c < NCH; c += 3) {
        if (c + 2 < NCH) loadChunk(eA, bA, c + 2);
        { RUN16(eB, bB, 0) }
        if (c + 3 < NCH) loadChunk(eB, bB, c + 3);
        if (c + 1 < NCH) { RUN16(eC, bC, 0) }
        if (c + 4 < NCH) loadChunk(eC, bC, c + 4);
        if (c + 2 < NCH) { RUN16(eA, bA, 0) }
    }
#undef RUN16

    // final: alpha[2len] at lane 2len-1, alpha[2len-1] at lane 2len-2
    float vhi = rdlane(A, i2 - 1);
    float vlo = rdlane(A, i2 - 2);
    float loss = -LN2 * (log2f(vhi + vlo) + (float)off);

    int ticket = 0;
    if (lane == 0) {
        if (p < BB) __hip_atomic_store(&lm[p], loss, __ATOMIC_RELEASE, __HIP_MEMORY_SCOPE_AGENT);
        else        __hip_atomic_store(&ls[p - BB], loss, __ATOMIC_RELEASE, __HIP_MEMORY_SCOPE_AGENT);
        ticket = __hip_atomic_fetch_add(counter, 1, __ATOMIC_ACQ_REL, __HIP_MEMORY_SCOPE_AGENT);
    }
    ticket = __builtin_amdgcn_readfirstlane(ticket);
    if (ticket == NPROB - 1) {
        // last block: finalize with this single wave (64 lanes)
        float lmv = __hip_atomic_load(&lm[lane], __ATOMIC_ACQUIRE, __HIP_MEMORY_SCOPE_AGENT);
        float msum = wave_sum(lmv / (float)length[lane]);
        float ssum = 0.f;
#pragma unroll
        for (int q = 0; q < 4; ++q) {
            int i = lane + q * 64;           // 0..255
            float lsv = __hip_atomic_load(&ls[i], __ATOMIC_ACQUIRE, __HIP_MEMORY_SCOPE_AGENT);
            float lmb = __hip_atomic_load(&lm[i >> 2], __ATOMIC_ACQUIRE, __HIP_MEMORY_SCOPE_AGENT);
            float conf = expf(-lmb);
            float r = 0.01f + 0.99f * (1.f - conf) * (1.f - conf);
            int sl = slength[i]; if (sl < 1) sl = 1;
            ssum += r * lsv / (float)sl;
        }
        ssum = wave_sum(ssum);
        if (lane == 0)
            out[0] = msum / (float)BB + 0.1f * (ssum / (float)(BB * COR));
    }
}

// ---------------------------------------------------------------------------
// Fallback path (only if ws too small) — round-3 log-domain kernels (proven).
// ---------------------------------------------------------------------------
__global__ __launch_bounds__(256) void lse_kernel(const float* __restrict__ preds,
                                                  float* __restrict__ lse) {
    int wave = (blockIdx.x * blockDim.x + threadIdx.x) >> 6;
    int lane = threadIdx.x & 63;
    if (wave >= BB * TT) return;
    const float4* row = (const float4*)(preds + (size_t)wave * CC);
    float v[16];
#pragma unroll
    for (int i = 0; i < 4; ++i) {
        int idx = lane + i * 64;
        float4 x = (idx < 250) ? row[idx] : make_float4(NEGV, NEGV, NEGV, NEGV);
        v[i*4+0] = x.x; v[i*4+1] = x.y; v[i*4+2] = x.z; v[i*4+3] = x.w;
    }
    float m = v[0];
#pragma unroll
    for (int i = 1; i < 16; ++i) m = fmaxf(m, v[i]);
#pragma unroll
    for (int off = 32; off; off >>= 1) m = fmaxf(m, __shfl_xor(m, off));
    float s = 0.f;
#pragma unroll
    for (int i = 0; i < 16; ++i) s += exp2f((v[i] - m) * LOG2E);
#pragma unroll
    for (int off = 32; off; off >>= 1) s += __shfl_xor(s, off);
    if (lane == 0) lse[wave] = m + log2f(s) * LN2;
}

__global__ __launch_bounds__(64) void ctc_kernel(const float* __restrict__ preds,
                                                 const float* __restrict__ lse,
                                                 const int* __restrict__ text,
                                                 const int* __restrict__ length,
                                                 const int* __restrict__ stext,
                                                 const int* __restrict__ slength,
                                                 float* __restrict__ lm,
                                                 float* __restrict__ ls) {
    const int p = blockIdx.x;
    const int lane = threadIdx.x;
    int b, len;
    const int* tgt;
    if (p < BB) { b = p;        tgt = text  + (size_t)p * SS; len = length[p]; }
    else { int i = p - BB; b = i / COR; tgt = stext + (size_t)i * SS; len = slength[i]; }
    const int s = lane;
    int cls = (s & 1) ? tgt[(s - 1) >> 1] : 0;
    bool use2 = false;
    if ((s & 1) && s >= 3) use2 = (cls != tgt[(s - 3) >> 1]);
    const float* pcls = preds + (size_t)b * TT * CC + cls;
    const float* lrow = lse + (size_t)b * TT;
    float ksum = 0.f;
#pragma unroll
    for (int i = 0; i < TT / 64; ++i) ksum += lrow[lane + i * 64];
#pragma unroll
    for (int off = 32; off; off >>= 1) ksum += __shfl_xor(ksum, off);
    float a, a64 = NEGV;
    constexpr int CH = 8;
    constexpr int NCH = TT / CH;
    float pvA[CH], pvB[CH];
    auto loadChunk = [&](float (&pv)[CH], int c) {
#pragma unroll
        for (int j = 0; j < CH; ++j) pv[j] = pcls[(size_t)(c * CH + j) * CC];
    };
    auto step = [&](float ev) {
        float p1 = dpp_shr1_fill(a, NEGV);
        float p2 = dpp_shr1_fill(p1, NEGV);
        float x2 = use2 ? p2 : NEGV;
        float m3 = fmaxf(fmaxf(a, p1), x2);
        float ss = exp2f((a - m3) * LOG2E) + exp2f((p1 - m3) * LOG2E) + exp2f((x2 - m3) * LOG2E);
        float a63 = rdlane(a, 63);
        float eb  = rdlane(ev, 0);
        float m2 = fmaxf(a64, a63);
        a64 = m2 + log2f(exp2f((a64 - m2) * LOG2E) + exp2f((a63 - m2) * LOG2E)) * LN2 + eb;
        a = m3 + log2f(ss) * LN2 + ev;
    };
    loadChunk(pvA, 0);
    loadChunk(pvB, 1);
    a = (s < 2) ? pvA[0] : NEGV;
#pragma unroll
    for (int j = 1; j < CH; ++j) step(pvA[j]);
    for (int c = 1; c < NCH; c += 2) {
        if (c + 1 < NCH) loadChunk(pvA, c + 1);
#pragma unroll
        for (int j = 0; j < CH; ++j) step(pvB[j]);
        if (c + 1 < NCH) {
            if (c + 2 < NCH) loadChunk(pvB, c + 2);
#pragma unroll
            for (int j = 0; j < CH; ++j) step(pvA[j]);
        }
    }
    int idx = 2 * len;
    float vhi = (idx < 64) ? rdlane(a, idx) : a64;
    float vlo = rdlane(a, idx - 1);
    float mm = fmaxf(vhi, vlo);
    float lae = mm + log2f(exp2f((vhi - mm) * LOG2E) + exp2f((vlo - mm) * LOG2E)) * LN2;
    float loss = ksum - lae;
    if (lane == 0) {
        if (p < BB) lm[p] = loss;
        else        ls[p - BB] = loss;
    }
}

__global__ __launch_bounds__(256) void fin_kernel(const float* __restrict__ lm,
                                                  const float* __restrict__ ls,
                                                  const int* __restrict__ length,
                                                  const int* __restrict__ slength,
                                                  float* __restrict__ out) {
    __shared__ float red[256];
    const int tid = threadIdx.x;

    float mterm = 0.f;
    if (tid < BB) mterm = lm[tid] / (float)length[tid];

    int bb = tid >> 2;
    float conf = expf(-lm[bb]);
    float r = 0.01f + 0.99f * (1.f - conf) * (1.f - conf);
    int sl = slength[tid]; if (sl < 1) sl = 1;
    float sterm = r * ls[tid] / (float)sl;

    red[tid] = mterm; __syncthreads();
    for (int off = 128; off; off >>= 1) {
        if (tid < off) red[tid] += red[tid + off];
        __syncthreads();
    }
    float sum_m = red[0];
    __syncthreads();

    red[tid] = sterm; __syncthreads();
    for (int off = 128; off; off >>= 1) {
        if (tid < off) red[tid] += red[tid + off];
        __syncthreads();
    }
    if (tid == 0)
        out[0] = sum_m / (float)BB + 0.1f * (red[0] / (float)(BB * COR));
}

// ---------------------------------------------------------------------------
extern "C" void kernel_launch(void* const* d_in, const int* in_sizes, int n_in,
                              void* d_out, int out_size, void* d_ws, size_t ws_size,
                              hipStream_t stream) {
    const float* preds   = (const float*)d_in[0];
    const int*   text    = (const int*)d_in[1];
    const int*   length  = (const int*)d_in[2];
    const int*   stext   = (const int*)d_in[3];
    const int*   slength = (const int*)d_in[4];
    float* out = (float*)d_out;

    size_t need = ((size_t)BB * TT + BB + BB * COR + 4 + (size_t)NPROB * TT * SS) * sizeof(float);

    if (ws_size >= need) {
        float* blankE  = (float*)d_ws;           // 64*512
        float* lm      = blankE + BB * TT;       // 64
        float* ls      = lm + BB;                // 256
        int*   counter = (int*)(ls + BB * COR);  // 4 slots (alignment pad)
        float* labels  = ls + BB * COR + 4;      // 320*512*32 (16B-aligned)

        gather_kernel<<<(BB * TT) / 4, 256, 0, stream>>>(preds, text, stext, labels, blankE, counter);
        ctc_lin_kernel<<<NPROB, 64, 0, stream>>>(labels, blankE, text, length, stext, slength,
                                                 lm, ls, counter, out);
    } else {
        float* lse = (float*)d_ws;
        float* lm  = lse + BB * TT;
        float* ls  = lm + BB;
        lse_kernel<<<(BB * TT) / 4, 256, 0, stream>>>(preds, lse);
        ctc_kernel<<<NPROB, 64, 0, stream>>>(preds, lse, text, length, stext, slength, lm, ls);
        fin_kernel<<<1, 256, 0, stream>>>(lm, ls, length, slength, out);
    }
}

// Round 9
// 73.680 us; speedup vs baseline: 1.0141x; 1.0141x over previous
//
#include <hip/hip_runtime.h>
#include <cmath>

#define BB 64
#define TT 512
#define CC 1000
#define SS 32
#define COR 4
#define NPROB (BB + BB*COR)   // 320
#define NEGV (-1e30f)
#define LOG2E 1.4426950408889634f
#define LN2 0.6931471805599453f
#define BIAS 50               // renorm target exponent: needed-max -> 2^BIAS
#define SHIFT 16.0f           // constant lse shift (replaces wave max; |w|<=8)

// ---------------------------------------------------------------------------
// DPP helpers (VALU-pipe cross-lane). 0x138 = wave_shr:1 (HW-verified r3-r8).
// Reduction tree row_shr:1/2/4/8 + row_bcast:15/31 -> lane 63 (HW-verified).
// ---------------------------------------------------------------------------
__device__ __forceinline__ float dpp_shr1_fill(float x, float fill) {
    int r = __builtin_amdgcn_update_dpp(__builtin_bit_cast(int, fill),
                                        __builtin_bit_cast(int, x),
                                        0x138, 0xf, 0xf, false);   // lane0 <- fill
    return __builtin_bit_cast(float, r);
}
__device__ __forceinline__ float dpp_shr1_z(float x) {
    int r = __builtin_amdgcn_update_dpp(0, __builtin_bit_cast(int, x),
                                        0x138, 0xf, 0xf, true);    // lane0 <- 0
    return __builtin_bit_cast(float, r);
}
template<int CTRL>
__device__ __forceinline__ float dpp_maxf(float m) {   // 0-fill ok: A >= 0
    int r = __builtin_amdgcn_update_dpp(0, __builtin_bit_cast(int, m),
                                        CTRL, 0xf, 0xf, true);
    return fmaxf(m, __builtin_bit_cast(float, r));
}
template<int CTRL>
__device__ __forceinline__ float dpp_addf(float s) {
    int r = __builtin_amdgcn_update_dpp(0, __builtin_bit_cast(int, s),
                                        CTRL, 0xf, 0xf, true);     // invalid -> +0
    return s + __builtin_bit_cast(float, r);
}
__device__ __forceinline__ float rdlane(float x, int lane) {
    return __builtin_bit_cast(float, __builtin_amdgcn_readlane(__builtin_bit_cast(int, x), lane));
}
// exact full-wave sum, result broadcast via readlane 63
__device__ __forceinline__ float wave_sum(float s) {
    s = dpp_addf<0x111>(s);
    s = dpp_addf<0x112>(s);
    s = dpp_addf<0x114>(s);
    s = dpp_addf<0x118>(s);
    s = dpp_addf<0x142>(s);
    s = dpp_addf<0x143>(s);
    return rdlane(s, 63);
}

// Renorm vs max over NEEDED lanes (lane < nl), all-VALU (~40cy).
// Scales so needed-max exponent == BIAS; accumulates true exponent in off.
__device__ __forceinline__ void renorm(float &A, float &a0, int &off,
                                       int lane, int nl) {
    float m = (lane < nl) ? A : 0.f;
    m = dpp_maxf<0x111>(m);
    m = dpp_maxf<0x112>(m);
    m = dpp_maxf<0x114>(m);
    m = dpp_maxf<0x118>(m);
    m = dpp_maxf<0x142>(m);
    m = dpp_maxf<0x143>(m);
    int mb = __builtin_amdgcn_readlane(__builtin_bit_cast(int, m), 63);
    int e = ((mb >> 23) & 0xff) - 127 - BIAS;
    e = (mb & 0x7fffffff) ? e : 0;       // m==0 guard
    A  = ldexpf(A,  -e);
    a0 = ldexpf(a0, -e);
    off += e;
}

// ---------------------------------------------------------------------------
// Gather kernel: per preds row [b,t,:]: coalesced float4 read; constant-shift
// exp2 sum (no max pass -- N(0,1) logits give |x*log2e| <= ~8, so w-16 is
// overflow/underflow-safe and exps overlap the loads); DPP wave_sum; write
// LINEAR normalized probs labels16[pid][t][k] (fp16, 64B/row) + blankE[b][t]
// (fp32, keeps the a0 recurrence full-precision).
// ---------------------------------------------------------------------------
__global__ __launch_bounds__(256) void gather_kernel(const float* __restrict__ preds,
                                                     const int* __restrict__ text,
                                                     const int* __restrict__ stext,
                                                     _Float16* __restrict__ labels,
                                                     float* __restrict__ blankE) {
    int gw = (blockIdx.x * blockDim.x + threadIdx.x) >> 6;   // row = b*512+t
    int lane = threadIdx.x & 63;
    if (gw >= BB * TT) return;
    int b = gw >> 9;
    int t = gw & (TT - 1);
    const float* row = preds + (size_t)gw * CC;
    const float4* row4 = (const float4*)row;
    float s = 0.f;
#pragma unroll
    for (int i = 0; i < 4; ++i) {
        int idx = lane + i * 64;
        float4 x = (idx < 250) ? row4[idx] : make_float4(NEGV, NEGV, NEGV, NEGV);
        s += exp2f(fmaf(x.x, LOG2E, -SHIFT));
        s += exp2f(fmaf(x.y, LOG2E, -SHIFT));
        s += exp2f(fmaf(x.z, LOG2E, -SHIFT));
        s += exp2f(fmaf(x.w, LOG2E, -SHIFT));
    }
    s = wave_sum(s);
    float lse2 = SHIFT + log2f(s);           // wave-uniform log2(sum exp2)

    if (lane == 0) blankE[gw] = exp2f(fmaf(row[0], LOG2E, -lse2));

#pragma unroll
    for (int it = 0; it < 3; ++it) {
        int g = lane + it * 64;
        if (g < 5 * SS) {
            int pp = g >> 5, k = g & 31;
            int cls, pid;
            if (pp == 0) { cls = text[b * SS + k]; pid = b; }
            else { int i = b * COR + (pp - 1); cls = stext[i * SS + k]; pid = BB + i; }
            labels[((size_t)pid * TT + t) * SS + k] =
                (_Float16)exp2f(fmaf(row[cls], LOG2E, -lse2));
        }
    }
}

// ---------------------------------------------------------------------------
// Linear-domain CTC (r7-proven 2-buffer schedule). Lane s owns extended
// position s+1; position 0 (leading blank) is the wave-uniform scalar a0
// (DPP fill operand). Per-step: dpp, dpp, cndmask, add, add, mul + one
// v_cvt_f32_f16 -- zero transcendentals. Even lanes stream fp16 labels
// (raw ushort prefetch buffers, convert at use); odd lanes reuse the
// float4-loaded blank chunk (no separate load stream). Renorm every 8 steps.
// loss = -ln2 * (log2(A[2len-1] + A[2len-2]) + off)  (emits pre-normalized).
// ---------------------------------------------------------------------------
__global__ __launch_bounds__(64) void ctc_lin_kernel(const _Float16* __restrict__ labels,
                                                     const float* __restrict__ blankE,
                                                     const int* __restrict__ text,
                                                     const int* __restrict__ length,
                                                     const int* __restrict__ stext,
                                                     const int* __restrict__ slength,
                                                     float* __restrict__ lm,
                                                     float* __restrict__ ls) {
    const int p = blockIdx.x;
    const int lane = threadIdx.x;

    int b, len;
    const int* tgt;
    if (p < BB) { b = p;        tgt = text  + (size_t)p * SS; len = length[p]; }
    else { int i = p - BB; b = i / COR; tgt = stext + (size_t)i * SS; len = slength[i]; }

    // lane s = position s+1: even s -> label k=s/2; odd s -> blank.
    const bool evenl = !(lane & 1);
    const int k = lane >> 1;
    bool use2 = false;
    if (evenl && lane >= 2) use2 = (tgt[k] != tgt[k - 1]);

    const float* bbase = blankE + (size_t)b * TT;
    const _Float16* lbase = labels + (size_t)p * TT * SS + k;   // even lanes
    const int i2 = 2 * len;                  // needed lanes: [0, i2)

    constexpr int CH = 16;
    constexpr int NCH = TT / CH;             // 32
    _Float16 eA[CH], eB[CH];
    float bA[CH], bB[CH];

    auto loadChunk = [&](_Float16 (&ee)[CH], float (&bv)[CH], int c) {
        if (evenl) {
#pragma unroll
            for (int j = 0; j < CH; ++j)
                ee[j] = lbase[(size_t)(c * CH + j) * SS];
        }
        const float4* b4 = (const float4*)(bbase + c * CH);
#pragma unroll
        for (int q = 0; q < CH / 4; ++q) {
            float4 y = b4[q];
            bv[q*4+0] = y.x; bv[q*4+1] = y.y; bv[q*4+2] = y.z; bv[q*4+3] = y.w;
        }
    };

    float A, a0;
    int off = 0;

#define RUN16(EE, BV, START)                                    \
    _Pragma("unroll")                                           \
    for (int j = (START); j < CH; ++j) {                        \
        float ev = evenl ? (float)EE[j] : BV[j];                \
        float p1 = dpp_shr1_fill(A, a0);                        \
        float p2 = dpp_shr1_z(p1);                              \
        float x2 = use2 ? p2 : 0.f;                             \
        A = (A + p1 + x2) * ev;                                 \
        a0 *= BV[j];                                            \
        if ((j & 7) == 7) renorm(A, a0, off, lane, i2);         \
    }

    // prologue: chunk 0 (t=0 is init), chunk 1 prefetched
    loadChunk(eA, bA, 0);
    loadChunk(eB, bB, 1);
    A  = (lane == 0) ? (float)eA[0] : 0.f;   // alpha0[pos1] = emit(y1); lane0 even
    a0 = bA[0];                              // alpha0[pos0] = emit(blank)
    RUN16(eA, bA, 1)

    for (int c = 1; c < NCH; c += 2) {
        if (c + 1 < NCH) loadChunk(eA, bA, c + 1);
        RUN16(eB, bB, 0)
        if (c + 1 < NCH) {
            if (c + 2 < NCH) loadChunk(eB, bB, c + 2);
            RUN16(eA, bA, 0)
        }
    }
#undef RUN16

    // final: alpha[2len] at lane 2len-1, alpha[2len-1] at lane 2len-2
    float vhi = rdlane(A, i2 - 1);
    float vlo = rdlane(A, i2 - 2);
    float loss = -LN2 * (log2f(vhi + vlo) + (float)off);

    if (lane == 0) {
        if (p < BB) lm[p] = loss;
        else        ls[p - BB] = loss;
    }
}

// ---------------------------------------------------------------------------
// Fallback path (only if ws too small) — round-3 log-domain kernels (proven).
// ---------------------------------------------------------------------------
__global__ __launch_bounds__(256) void lse_kernel(const float* __restrict__ preds,
                                                  float* __restrict__ lse) {
    int wave = (blockIdx.x * blockDim.x + threadIdx.x) >> 6;
    int lane = threadIdx.x & 63;
    if (wave >= BB * TT) return;
    const float4* row = (const float4*)(preds + (size_t)wave * CC);
    float v[16];
#pragma unroll
    for (int i = 0; i < 4; ++i) {
        int idx = lane + i * 64;
        float4 x = (idx < 250) ? row[idx] : make_float4(NEGV, NEGV, NEGV, NEGV);
        v[i*4+0] = x.x; v[i*4+1] = x.y; v[i*4+2] = x.z; v[i*4+3] = x.w;
    }
    float m = v[0];
#pragma unroll
    for (int i = 1; i < 16; ++i) m = fmaxf(m, v[i]);
#pragma unroll
    for (int off = 32; off; off >>= 1) m = fmaxf(m, __shfl_xor(m, off));
    float s = 0.f;
#pragma unroll
    for (int i = 0; i < 16; ++i) s += exp2f((v[i] - m) * LOG2E);
#pragma unroll
    for (int off = 32; off; off >>= 1) s += __shfl_xor(s, off);
    if (lane == 0) lse[wave] = m + log2f(s) * LN2;
}

__global__ __launch_bounds__(64) void ctc_kernel(const float* __restrict__ preds,
                                                 const float* __restrict__ lse,
                                                 const int* __restrict__ text,
                                                 const int* __restrict__ length,
                                                 const int* __restrict__ stext,
                                                 const int* __restrict__ slength,
                                                 float* __restrict__ lm,
                                                 float* __restrict__ ls) {
    const int p = blockIdx.x;
    const int lane = threadIdx.x;
    int b, len;
    const int* tgt;
    if (p < BB) { b = p;        tgt = text  + (size_t)p * SS; len = length[p]; }
    else { int i = p - BB; b = i / COR; tgt = stext + (size_t)i * SS; len = slength[i]; }
    const int s = lane;
    int cls = (s & 1) ? tgt[(s - 1) >> 1] : 0;
    bool use2 = false;
    if ((s & 1) && s >= 3) use2 = (cls != tgt[(s - 3) >> 1]);
    const float* pcls = preds + (size_t)b * TT * CC + cls;
    const float* lrow = lse + (size_t)b * TT;
    float ksum = 0.f;
#pragma unroll
    for (int i = 0; i < TT / 64; ++i) ksum += lrow[lane + i * 64];
#pragma unroll
    for (int off = 32; off; off >>= 1) ksum += __shfl_xor(ksum, off);
    float a, a64 = NEGV;
    constexpr int CH = 8;
    constexpr int NCH = TT / CH;
    float pvA[CH], pvB[CH];
    auto loadChunk = [&](float (&pv)[CH], int c) {
#pragma unroll
        for (int j = 0; j < CH; ++j) pv[j] = pcls[(size_t)(c * CH + j) * CC];
    };
    auto step = [&](float ev) {
        float p1 = dpp_shr1_fill(a, NEGV);
        float p2 = dpp_shr1_fill(p1, NEGV);
        float x2 = use2 ? p2 : NEGV;
        float m3 = fmaxf(fmaxf(a, p1), x2);
        float ss = exp2f((a - m3) * LOG2E) + exp2f((p1 - m3) * LOG2E) + exp2f((x2 - m3) * LOG2E);
        float a63 = rdlane(a, 63);
        float eb  = rdlane(ev, 0);
        float m2 = fmaxf(a64, a63);
        a64 = m2 + log2f(exp2f((a64 - m2) * LOG2E) + exp2f((a63 - m2) * LOG2E)) * LN2 + eb;
        a = m3 + log2f(ss) * LN2 + ev;
    };
    loadChunk(pvA, 0);
    loadChunk(pvB, 1);
    a = (s < 2) ? pvA[0] : NEGV;
#pragma unroll
    for (int j = 1; j < CH; ++j) step(pvA[j]);
    for (int c = 1; c < NCH; c += 2) {
        if (c + 1 < NCH) loadChunk(pvA, c + 1);
#pragma unroll
        for (int j = 0; j < CH; ++j) step(pvB[j]);
        if (c + 1 < NCH) {
            if (c + 2 < NCH) loadChunk(pvB, c + 2);
#pragma unroll
            for (int j = 0; j < CH; ++j) step(pvA[j]);
        }
    }
    int idx = 2 * len;
    float vhi = (idx < 64) ? rdlane(a, idx) : a64;
    float vlo = rdlane(a, idx - 1);
    float mm = fmaxf(vhi, vlo);
    float lae = mm + log2f(exp2f((vhi - mm) * LOG2E) + exp2f((vlo - mm) * LOG2E)) * LN2;
    float loss = ksum - lae;
    if (lane == 0) {
        if (p < BB) lm[p] = loss;
        else        ls[p - BB] = loss;
    }
}

// ---------------------------------------------------------------------------
// Finalize scalar loss (r7-proven separate kernel; no cross-XCD atomics).
// ---------------------------------------------------------------------------
__global__ __launch_bounds__(256) void fin_kernel(const float* __restrict__ lm,
                                                  const float* __restrict__ ls,
                                                  const int* __restrict__ length,
                                                  const int* __restrict__ slength,
                                                  float* __restrict__ out) {
    __shared__ float red[256];
    const int tid = threadIdx.x;

    float mterm = 0.f;
    if (tid < BB) mterm = lm[tid] / (float)length[tid];

    int bb = tid >> 2;
    float conf = expf(-lm[bb]);
    float r = 0.01f + 0.99f * (1.f - conf) * (1.f - conf);
    int sl = slength[tid]; if (sl < 1) sl = 1;
    float sterm = r * ls[tid] / (float)sl;

    red[tid] = mterm; __syncthreads();
    for (int off = 128; off; off >>= 1) {
        if (tid < off) red[tid] += red[tid + off];
        __syncthreads();
    }
    float sum_m = red[0];
    __syncthreads();

    red[tid] = sterm; __syncthreads();
    for (int off = 128; off; off >>= 1) {
        if (tid < off) red[tid] += red[tid + off];
        __syncthreads();
    }
    if (tid == 0)
        out[0] = sum_m / (float)BB + 0.1f * (red[0] / (float)(BB * COR));
}

// ---------------------------------------------------------------------------
extern "C" void kernel_launch(void* const* d_in, const int* in_sizes, int n_in,
                              void* d_out, int out_size, void* d_ws, size_t ws_size,
                              hipStream_t stream) {
    const float* preds   = (const float*)d_in[0];
    const int*   text    = (const int*)d_in[1];
    const int*   length  = (const int*)d_in[2];
    const int*   stext   = (const int*)d_in[3];
    const int*   slength = (const int*)d_in[4];
    float* out = (float*)d_out;

    size_t need = ((size_t)BB * TT + BB + BB * COR) * sizeof(float)
                + (size_t)NPROB * TT * SS * sizeof(_Float16);

    if (ws_size >= need) {
        float*     blankE = (float*)d_ws;              // 64*512 f32
        float*     lm     = blankE + BB * TT;          // 64
        float*     ls     = lm + BB;                   // 256
        _Float16*  labels = (_Float16*)(ls + BB * COR);// 320*512*32 fp16

        gather_kernel<<<(BB * TT) / 4, 256, 0, stream>>>(preds, text, stext, labels, blankE);
        ctc_lin_kernel<<<NPROB, 64, 0, stream>>>(labels, blankE, text, length, stext, slength, lm, ls);
        fin_kernel<<<1, 256, 0, stream>>>(lm, ls, length, slength, out);
    } else {
        float* lse = (float*)d_ws;
        float* lm  = lse + BB * TT;
        float* ls  = lm + BB;
        lse_kernel<<<(BB * TT) / 4, 256, 0, stream>>>(preds, lse);
        ctc_kernel<<<NPROB, 64, 0, stream>>>(preds, lse, text, length, stext, slength, lm, ls);
        fin_kernel<<<1, 256, 0, stream>>>(lm, ls, length, slength, out);
    }
}

// Round 10
// 65.951 us; speedup vs baseline: 1.1329x; 1.1172x over previous
//
#include <hip/hip_runtime.h>
#include <cmath>

#define BB 64
#define TT 512
#define CC 1000
#define SS 32
#define COR 4
#define NPROB (BB + BB*COR)   // 320
#define NEGV (-1e30f)
#define LOG2E 1.4426950408889634f
#define LN2 0.6931471805599453f
#define BIAS 50               // renorm target exponent: needed-max -> 2^BIAS
#define SHIFT 16.0f           // constant lse shift (replaces wave max; |w|<=8)

// ---------------------------------------------------------------------------
// DPP helpers (VALU-pipe cross-lane). 0x138 = wave_shr:1 (HW-verified r3-r9).
// Reduction tree row_shr:1/2/4/8 + row_bcast:15/31 -> lane 63 (HW-verified).
// ---------------------------------------------------------------------------
__device__ __forceinline__ float dpp_shr1_fill(float x, float fill) {
    int r = __builtin_amdgcn_update_dpp(__builtin_bit_cast(int, fill),
                                        __builtin_bit_cast(int, x),
                                        0x138, 0xf, 0xf, false);   // lane0 <- fill
    return __builtin_bit_cast(float, r);
}
__device__ __forceinline__ float dpp_shr1_z(float x) {
    int r = __builtin_amdgcn_update_dpp(0, __builtin_bit_cast(int, x),
                                        0x138, 0xf, 0xf, true);    // lane0 <- 0
    return __builtin_bit_cast(float, r);
}
template<int CTRL>
__device__ __forceinline__ float dpp_maxf(float m) {   // 0-fill ok: A >= 0
    int r = __builtin_amdgcn_update_dpp(0, __builtin_bit_cast(int, m),
                                        CTRL, 0xf, 0xf, true);
    return fmaxf(m, __builtin_bit_cast(float, r));
}
template<int CTRL>
__device__ __forceinline__ float dpp_addf(float s) {
    int r = __builtin_amdgcn_update_dpp(0, __builtin_bit_cast(int, s),
                                        CTRL, 0xf, 0xf, true);     // invalid -> +0
    return s + __builtin_bit_cast(float, r);
}
__device__ __forceinline__ float rdlane(float x, int lane) {
    return __builtin_bit_cast(float, __builtin_amdgcn_readlane(__builtin_bit_cast(int, x), lane));
}
// exact full-wave sum, result broadcast via readlane 63
__device__ __forceinline__ float wave_sum(float s) {
    s = dpp_addf<0x111>(s);
    s = dpp_addf<0x112>(s);
    s = dpp_addf<0x114>(s);
    s = dpp_addf<0x118>(s);
    s = dpp_addf<0x142>(s);
    s = dpp_addf<0x143>(s);
    return rdlane(s, 63);
}

// Renorm vs max over NEEDED lanes (lane < nl), all-VALU (~40cy).
// Scales so needed-max exponent == BIAS; accumulates true exponent in off.
__device__ __forceinline__ void renorm(float &A, float &a0, int &off,
                                       int lane, int nl) {
    float m = (lane < nl) ? A : 0.f;
    m = dpp_maxf<0x111>(m);
    m = dpp_maxf<0x112>(m);
    m = dpp_maxf<0x114>(m);
    m = dpp_maxf<0x118>(m);
    m = dpp_maxf<0x142>(m);
    m = dpp_maxf<0x143>(m);
    int mb = __builtin_amdgcn_readlane(__builtin_bit_cast(int, m), 63);
    int e = ((mb >> 23) & 0xff) - 127 - BIAS;
    e = (mb & 0x7fffffff) ? e : 0;       // m==0 guard
    A  = ldexpf(A,  -e);
    a0 = ldexpf(a0, -e);
    off += e;
}

// ---------------------------------------------------------------------------
// Gather kernel: per preds row [b,t,:]: coalesced float4 read; constant-shift
// exp2 sum (no max pass -- N(0,1) logits give |x*log2e| <= ~8, so w-16 is
// overflow/underflow-safe and exps overlap the loads); DPP wave_sum; write
// LINEAR normalized probs labels[pid][t][k] (fp32, 5 x 128B lines/row) and
// blankE[b][t].
// ---------------------------------------------------------------------------
__global__ __launch_bounds__(256) void gather_kernel(const float* __restrict__ preds,
                                                     const int* __restrict__ text,
                                                     const int* __restrict__ stext,
                                                     float* __restrict__ labels,
                                                     float* __restrict__ blankE) {
    int gw = (blockIdx.x * blockDim.x + threadIdx.x) >> 6;   // row = b*512+t
    int lane = threadIdx.x & 63;
    if (gw >= BB * TT) return;
    int b = gw >> 9;
    int t = gw & (TT - 1);
    const float* row = preds + (size_t)gw * CC;
    const float4* row4 = (const float4*)row;
    float s = 0.f;
#pragma unroll
    for (int i = 0; i < 4; ++i) {
        int idx = lane + i * 64;
        float4 x = (idx < 250) ? row4[idx] : make_float4(NEGV, NEGV, NEGV, NEGV);
        s += exp2f(fmaf(x.x, LOG2E, -SHIFT));
        s += exp2f(fmaf(x.y, LOG2E, -SHIFT));
        s += exp2f(fmaf(x.z, LOG2E, -SHIFT));
        s += exp2f(fmaf(x.w, LOG2E, -SHIFT));
    }
    s = wave_sum(s);
    float lse2 = SHIFT + log2f(s);           // wave-uniform log2(sum exp2)

    if (lane == 0) blankE[gw] = exp2f(fmaf(row[0], LOG2E, -lse2));

#pragma unroll
    for (int it = 0; it < 3; ++it) {
        int g = lane + it * 64;
        if (g < 5 * SS) {
            int pp = g >> 5, k = g & 31;
            int cls, pid;
            if (pp == 0) { cls = text[b * SS + k]; pid = b; }
            else { int i = b * COR + (pp - 1); cls = stext[i * SS + k]; pid = BB + i; }
            labels[((size_t)pid * TT + t) * SS + k] = exp2f(fmaf(row[cls], LOG2E, -lse2));
        }
    }
}

// ---------------------------------------------------------------------------
// Linear-domain CTC (r7-proven 2-buffer schedule; r9's odd-lane bv-reuse).
// Lane s owns extended position s+1; position 0 (leading blank) is the
// wave-uniform scalar a0 (DPP fill operand). Per-step: dpp, dpp, cndmask x2,
// add, add, mul -- zero transcendentals. Even lanes stream fp32 labels;
// odd lanes reuse the float4-loaded blank chunk (no separate load stream).
// Renorm (DPP tree, needed-lane max -> 2^BIAS) every 8 steps.
// loss = -ln2 * (log2(A[2len-1] + A[2len-2]) + off)  (emits pre-normalized).
// ---------------------------------------------------------------------------
__global__ __launch_bounds__(64) void ctc_lin_kernel(const float* __restrict__ labels,
                                                     const float* __restrict__ blankE,
                                                     const int* __restrict__ text,
                                                     const int* __restrict__ length,
                                                     const int* __restrict__ stext,
                                                     const int* __restrict__ slength,
                                                     float* __restrict__ lm,
                                                     float* __restrict__ ls) {
    const int p = blockIdx.x;
    const int lane = threadIdx.x;

    int b, len;
    const int* tgt;
    if (p < BB) { b = p;        tgt = text  + (size_t)p * SS; len = length[p]; }
    else { int i = p - BB; b = i / COR; tgt = stext + (size_t)i * SS; len = slength[i]; }

    // lane s = position s+1: even s -> label k=s/2; odd s -> blank.
    const bool evenl = !(lane & 1);
    const int k = lane >> 1;
    bool use2 = false;
    if (evenl && lane >= 2) use2 = (tgt[k] != tgt[k - 1]);

    const float* bbase = blankE + (size_t)b * TT;
    const float* lbase = labels + (size_t)p * TT * SS + k;     // even lanes
    const int i2 = 2 * len;                  // needed lanes: [0, i2)

    constexpr int CH = 16;
    constexpr int NCH = TT / CH;             // 32
    float eA[CH], eB[CH], bA[CH], bB[CH];

    auto loadChunk = [&](float (&ee)[CH], float (&bv)[CH], int c) {
        if (evenl) {
#pragma unroll
            for (int j = 0; j < CH; ++j)
                ee[j] = lbase[(size_t)(c * CH + j) * SS];
        }
        const float4* b4 = (const float4*)(bbase + c * CH);
#pragma unroll
        for (int q = 0; q < CH / 4; ++q) {
            float4 y = b4[q];
            bv[q*4+0] = y.x; bv[q*4+1] = y.y; bv[q*4+2] = y.z; bv[q*4+3] = y.w;
        }
    };

    float A, a0;
    int off = 0;

#define RUN16(EE, BV, START)                                    \
    _Pragma("unroll")                                           \
    for (int j = (START); j < CH; ++j) {                        \
        float ev = evenl ? EE[j] : BV[j];                       \
        float p1 = dpp_shr1_fill(A, a0);                        \
        float p2 = dpp_shr1_z(p1);                              \
        float x2 = use2 ? p2 : 0.f;                             \
        A = (A + p1 + x2) * ev;                                 \
        a0 *= BV[j];                                            \
        if ((j & 7) == 7) renorm(A, a0, off, lane, i2);         \
    }

    // prologue: chunk 0 (t=0 is init), chunk 1 prefetched
    loadChunk(eA, bA, 0);
    loadChunk(eB, bB, 1);
    A  = (lane == 0) ? eA[0] : 0.f;          // alpha0[pos1] = emit(y1); lane0 even
    a0 = bA[0];                              // alpha0[pos0] = emit(blank)
    RUN16(eA, bA, 1)

    for (int c = 1; c < NCH; c += 2) {
        if (c + 1 < NCH) loadChunk(eA, bA, c + 1);
        RUN16(eB, bB, 0)
        if (c + 1 < NCH) {
            if (c + 2 < NCH) loadChunk(eB, bB, c + 2);
            RUN16(eA, bA, 0)
        }
    }
#undef RUN16

    // final: alpha[2len] at lane 2len-1, alpha[2len-1] at lane 2len-2
    float vhi = rdlane(A, i2 - 1);
    float vlo = rdlane(A, i2 - 2);
    float loss = -LN2 * (log2f(vhi + vlo) + (float)off);

    if (lane == 0) {
        if (p < BB) lm[p] = loss;
        else        ls[p - BB] = loss;
    }
}

// ---------------------------------------------------------------------------
// Fallback path (only if ws too small) — round-3 log-domain kernels (proven).
// ---------------------------------------------------------------------------
__global__ __launch_bounds__(256) void lse_kernel(const float* __restrict__ preds,
                                                  float* __restrict__ lse) {
    int wave = (blockIdx.x * blockDim.x + threadIdx.x) >> 6;
    int lane = threadIdx.x & 63;
    if (wave >= BB * TT) return;
    const float4* row = (const float4*)(preds + (size_t)wave * CC);
    float v[16];
#pragma unroll
    for (int i = 0; i < 4; ++i) {
        int idx = lane + i * 64;
        float4 x = (idx < 250) ? row[idx] : make_float4(NEGV, NEGV, NEGV, NEGV);
        v[i*4+0] = x.x; v[i*4+1] = x.y; v[i*4+2] = x.z; v[i*4+3] = x.w;
    }
    float m = v[0];
#pragma unroll
    for (int i = 1; i < 16; ++i) m = fmaxf(m, v[i]);
#pragma unroll
    for (int off = 32; off; off >>= 1) m = fmaxf(m, __shfl_xor(m, off));
    float s = 0.f;
#pragma unroll
    for (int i = 0; i < 16; ++i) s += exp2f((v[i] - m) * LOG2E);
#pragma unroll
    for (int off = 32; off; off >>= 1) s += __shfl_xor(s, off);
    if (lane == 0) lse[wave] = m + log2f(s) * LN2;
}

__global__ __launch_bounds__(64) void ctc_kernel(const float* __restrict__ preds,
                                                 const float* __restrict__ lse,
                                                 const int* __restrict__ text,
                                                 const int* __restrict__ length,
                                                 const int* __restrict__ stext,
                                                 const int* __restrict__ slength,
                                                 float* __restrict__ lm,
                                                 float* __restrict__ ls) {
    const int p = blockIdx.x;
    const int lane = threadIdx.x;
    int b, len;
    const int* tgt;
    if (p < BB) { b = p;        tgt = text  + (size_t)p * SS; len = length[p]; }
    else { int i = p - BB; b = i / COR; tgt = stext + (size_t)i * SS; len = slength[i]; }
    const int s = lane;
    int cls = (s & 1) ? tgt[(s - 1) >> 1] : 0;
    bool use2 = false;
    if ((s & 1) && s >= 3) use2 = (cls != tgt[(s - 3) >> 1]);
    const float* pcls = preds + (size_t)b * TT * CC + cls;
    const float* lrow = lse + (size_t)b * TT;
    float ksum = 0.f;
#pragma unroll
    for (int i = 0; i < TT / 64; ++i) ksum += lrow[lane + i * 64];
#pragma unroll
    for (int off = 32; off; off >>= 1) ksum += __shfl_xor(ksum, off);
    float a, a64 = NEGV;
    constexpr int CH = 8;
    constexpr int NCH = TT / CH;
    float pvA[CH], pvB[CH];
    auto loadChunk = [&](float (&pv)[CH], int c) {
#pragma unroll
        for (int j = 0; j < CH; ++j) pv[j] = pcls[(size_t)(c * CH + j) * CC];
    };
    auto step = [&](float ev) {
        float p1 = dpp_shr1_fill(a, NEGV);
        float p2 = dpp_shr1_fill(p1, NEGV);
        float x2 = use2 ? p2 : NEGV;
        float m3 = fmaxf(fmaxf(a, p1), x2);
        float ss = exp2f((a - m3) * LOG2E) + exp2f((p1 - m3) * LOG2E) + exp2f((x2 - m3) * LOG2E);
        float a63 = rdlane(a, 63);
        float eb  = rdlane(ev, 0);
        float m2 = fmaxf(a64, a63);
        a64 = m2 + log2f(exp2f((a64 - m2) * LOG2E) + exp2f((a63 - m2) * LOG2E)) * LN2 + eb;
        a = m3 + log2f(ss) * LN2 + ev;
    };
    loadChunk(pvA, 0);
    loadChunk(pvB, 1);
    a = (s < 2) ? pvA[0] : NEGV;
#pragma unroll
    for (int j = 1; j < CH; ++j) step(pvA[j]);
    for (int c = 1; c < NCH; c += 2) {
        if (c + 1 < NCH) loadChunk(pvA, c + 1);
#pragma unroll
        for (int j = 0; j < CH; ++j) step(pvB[j]);
        if (c + 1 < NCH) {
            if (c + 2 < NCH) loadChunk(pvB, c + 2);
#pragma unroll
            for (int j = 0; j < CH; ++j) step(pvA[j]);
        }
    }
    int idx = 2 * len;
    float vhi = (idx < 64) ? rdlane(a, idx) : a64;
    float vlo = rdlane(a, idx - 1);
    float mm = fmaxf(vhi, vlo);
    float lae = mm + log2f(exp2f((vhi - mm) * LOG2E) + exp2f((vlo - mm) * LOG2E)) * LN2;
    float loss = ksum - lae;
    if (lane == 0) {
        if (p < BB) lm[p] = loss;
        else        ls[p - BB] = loss;
    }
}

// ---------------------------------------------------------------------------
// Finalize scalar loss (separate kernel; no cross-XCD atomics).
// ---------------------------------------------------------------------------
__global__ __launch_bounds__(256) void fin_kernel(const float* __restrict__ lm,
                                                  const float* __restrict__ ls,
                                                  const int* __restrict__ length,
                                                  const int* __restrict__ slength,
                                                  float* __restrict__ out) {
    __shared__ float red[256];
    const int tid = threadIdx.x;

    float mterm = 0.f;
    if (tid < BB) mterm = lm[tid] / (float)length[tid];

    int bb = tid >> 2;
    float conf = expf(-lm[bb]);
    float r = 0.01f + 0.99f * (1.f - conf) * (1.f - conf);
    int sl = slength[tid]; if (sl < 1) sl = 1;
    float sterm = r * ls[tid] / (float)sl;

    red[tid] = mterm; __syncthreads();
    for (int off = 128; off; off >>= 1) {
        if (tid < off) red[tid] += red[tid + off];
        __syncthreads();
    }
    float sum_m = red[0];
    __syncthreads();

    red[tid] = sterm; __syncthreads();
    for (int off = 128; off; off >>= 1) {
        if (tid < off) red[tid] += red[tid + off];
        __syncthreads();
    }
    if (tid == 0)
        out[0] = sum_m / (float)BB + 0.1f * (red[0] / (float)(BB * COR));
}

// ---------------------------------------------------------------------------
extern "C" void kernel_launch(void* const* d_in, const int* in_sizes, int n_in,
                              void* d_out, int out_size, void* d_ws, size_t ws_size,
                              hipStream_t stream) {
    const float* preds   = (const float*)d_in[0];
    const int*   text    = (const int*)d_in[1];
    const int*   length  = (const int*)d_in[2];
    const int*   stext   = (const int*)d_in[3];
    const int*   slength = (const int*)d_in[4];
    float* out = (float*)d_out;

    size_t need = ((size_t)BB * TT + BB + BB * COR + (size_t)NPROB * TT * SS) * sizeof(float);

    if (ws_size >= need) {
        float* blankE = (float*)d_ws;            // 64*512
        float* lm     = blankE + BB * TT;        // 64
        float* ls     = lm + BB;                 // 256
        float* labels = ls + BB * COR;           // 320*512*32 fp32 (16B-aligned)

        gather_kernel<<<(BB * TT) / 4, 256, 0, stream>>>(preds, text, stext, labels, blankE);
        ctc_lin_kernel<<<NPROB, 64, 0, stream>>>(labels, blankE, text, length, stext, slength, lm, ls);
        fin_kernel<<<1, 256, 0, stream>>>(lm, ls, length, slength, out);
    } else {
        float* lse = (float*)d_ws;
        float* lm  = lse + BB * TT;
        float* ls  = lm + BB;
        lse_kernel<<<(BB * TT) / 4, 256, 0, stream>>>(preds, lse);
        ctc_kernel<<<NPROB, 64, 0, stream>>>(preds, lse, text, length, stext, slength, lm, ls);
        fin_kernel<<<1, 256, 0, stream>>>(lm, ls, length, slength, out);
    }
}